// Round 4
// baseline (392.721 us; speedup 1.0000x reference)
//
#include <hip/hip_runtime.h>
#include <hip/hip_bf16.h>
#include <hip/hip_cooperative_groups.h>

namespace cg = cooperative_groups;

// Problem constants
#define HH 40
#define WW 40
#define KK 5
#define PP 1296            // 36*36
#define LL 25
#define MM 384
#define NN 64
#define NPTS (NN * PP)     // 82944
#define JITTER 1e-6f
#define NS_ITERS 7         // ||R0||^(2^7) << bf16 noise

typedef unsigned short u16;
typedef unsigned int   u32;
using short8  = __attribute__((ext_vector_type(8))) short;
using floatx4 = __attribute__((ext_vector_type(4))) float;

#define FRAG_N (MM * MM)        // u16 per frag half-array (147456)
#define ZFRAG_N (24 * 64 * 8)   // 12288
#define GRID_SETUP 72
#define GT (GRID_SETUP * 256)   // 18432 setup threads

// ---------------------------------------------------------------------------
// bf16 split helpers (RNE)
__device__ inline u16 f2bf(float v) {
    u32 b = __float_as_uint(v);
    return (u16)((b + 0x7FFFu + ((b >> 16) & 1u)) >> 16);
}
__device__ inline float bf2f(u16 h) { return __uint_as_float(((u32)h) << 16); }
__device__ inline void split_bf16(float v, u16& hi, u16& lo) {
    hi = f2bf(v);
    lo = f2bf(v - bf2f(hi));
}

// A-fragment linear index (u16 units) for element (m,k), HW-verified rounds 2-3.
__device__ inline int frag_idx(int m, int k) {
    return (((m >> 4) * 12 + (k >> 5)) * 64 + ((m & 15) + (((k >> 3) & 3) << 4))) * 8 + (k & 7);
}

// ---------------------------------------------------------------------------
// Split-bf16 MFMA 64x64-tile GEMM on A-frag operands: computes A @ B^T_storage
// (i.e. A @ B when B is stored as the A-frag of a symmetric matrix, or
//  P @ Q^T when Q is stored as the A-frag of Q).
__device__ inline void frag_gemm64(const u16* __restrict__ Ah, const u16* __restrict__ Al,
                                   const u16* __restrict__ Bh, const u16* __restrict__ Bl,
                                   int bi, int bj, int w, int l, floatx4 acc[2][2]) {
    int mt0 = bi * 4 + 2 * (w & 1);
    int nt0 = bj * 4 + 2 * (w >> 1);
#pragma unroll
    for (int i = 0; i < 2; ++i)
#pragma unroll
        for (int jn = 0; jn < 2; ++jn) { floatx4 z = {0.f, 0.f, 0.f, 0.f}; acc[i][jn] = z; }
    for (int kt = 0; kt < 12; ++kt) {
        int ab0 = (((mt0 + 0) * 12 + kt) * 64 + l) * 8;
        int ab1 = (((mt0 + 1) * 12 + kt) * 64 + l) * 8;
        int bb0 = (((nt0 + 0) * 12 + kt) * 64 + l) * 8;
        int bb1 = (((nt0 + 1) * 12 + kt) * 64 + l) * 8;
        short8 a0h = *(const short8*)&Ah[ab0];
        short8 a0l = *(const short8*)&Al[ab0];
        short8 a1h = *(const short8*)&Ah[ab1];
        short8 a1l = *(const short8*)&Al[ab1];
        short8 b0h = *(const short8*)&Bh[bb0];
        short8 b0l = *(const short8*)&Bl[bb0];
        short8 b1h = *(const short8*)&Bh[bb1];
        short8 b1l = *(const short8*)&Bl[bb1];
        acc[0][0] = __builtin_amdgcn_mfma_f32_16x16x32_bf16(a0h, b0h, acc[0][0], 0, 0, 0);
        acc[0][0] = __builtin_amdgcn_mfma_f32_16x16x32_bf16(a0h, b0l, acc[0][0], 0, 0, 0);
        acc[0][0] = __builtin_amdgcn_mfma_f32_16x16x32_bf16(a0l, b0h, acc[0][0], 0, 0, 0);
        acc[0][1] = __builtin_amdgcn_mfma_f32_16x16x32_bf16(a0h, b1h, acc[0][1], 0, 0, 0);
        acc[0][1] = __builtin_amdgcn_mfma_f32_16x16x32_bf16(a0h, b1l, acc[0][1], 0, 0, 0);
        acc[0][1] = __builtin_amdgcn_mfma_f32_16x16x32_bf16(a0l, b1h, acc[0][1], 0, 0, 0);
        acc[1][0] = __builtin_amdgcn_mfma_f32_16x16x32_bf16(a1h, b0h, acc[1][0], 0, 0, 0);
        acc[1][0] = __builtin_amdgcn_mfma_f32_16x16x32_bf16(a1h, b0l, acc[1][0], 0, 0, 0);
        acc[1][0] = __builtin_amdgcn_mfma_f32_16x16x32_bf16(a1l, b0h, acc[1][0], 0, 0, 0);
        acc[1][1] = __builtin_amdgcn_mfma_f32_16x16x32_bf16(a1h, b1h, acc[1][1], 0, 0, 0);
        acc[1][1] = __builtin_amdgcn_mfma_f32_16x16x32_bf16(a1h, b1l, acc[1][1], 0, 0, 0);
        acc[1][1] = __builtin_amdgcn_mfma_f32_16x16x32_bf16(a1l, b1h, acc[1][1], 0, 0, 0);
    }
}

__device__ inline void dwrite_frag(u16* __restrict__ Oh, u16* __restrict__ Ol,
                                   int m, int p, float v) {
    int idx = frag_idx(m, p);
    u16 hi, lo;
    split_bf16(v, hi, lo);
    Oh[idx] = hi; Ol[idx] = lo;
}

// ---------------------------------------------------------------------------
// ONE cooperative kernel for the whole setup chain (replaces 19 launches).
__global__ void __launch_bounds__(256) setup_kernel(
    const float* __restrict__ Z, const float* __restrict__ q_mu,
    const float* __restrict__ q_sqrt,
    const float* __restrict__ var_p, const float* __restrict__ ls_p,
    float* Kuu,
    u16* Xh_a, u16* Xl_a, u16* Xh_b, u16* Xl_b,
    u16* Rh_a, u16* Rl_a, u16* Rh_b, u16* Rl_b,
    u16* Bfh, u16* Bfl,          // stage A: Q frags; stage G: Bq frags
    u16* Zfh, u16* Zfl,
    float* z2g, float* cvec, float* rsum, float* alphag) {
    cg::grid_group grid = cg::this_grid();
    __shared__ float sbuf[MM];
    int tid = threadIdx.x, blk = blockIdx.x;
    int gid = blk * 256 + tid;
    float var = var_p[0];
    float ls = ls_p[0];
    float c0 = -0.5f / (ls * ls);

    // ---- Stage A: Kuu, z2, Z frags, Q frags (independent) ----
    for (int idx = gid; idx < MM * MM; idx += GT) {
        int i = idx / MM, j = idx % MM;
        float s = 0.f;
#pragma unroll
        for (int d = 0; d < LL; ++d) {
            float dd = Z[i * LL + d] - Z[j * LL + d];
            s += dd * dd;
        }
        float v = var * expf(s * c0);
        if (i == j) v += JITTER;
        Kuu[idx] = v;
    }
    if (gid < MM) {
        float s = 0.f;
#pragma unroll
        for (int d = 0; d < LL; ++d) { float z = Z[gid * LL + d]; s += z * z; }
        z2g[gid] = s;
    }
    for (int o = gid; o < ZFRAG_N; o += GT) {
        int j = o & 7, ln = (o >> 3) & 63, zt = o >> 9;
        int m = zt * 16 + (ln & 15);
        int kd = ((ln >> 4) << 3) + j;
        float v = (kd < LL) ? Z[m * LL + kd] : 0.f;
        u16 h, lo;
        split_bf16(v, h, lo);
        Zfh[o] = h; Zfl[o] = lo;
    }
    for (int o = gid; o < FRAG_N; o += GT) {   // Q = tril(q_sqrt) into Bf region
        int j = o & 7, ln = (o >> 3) & 63, kt = (o >> 9) % 12, mt = o / 6144;
        int m = mt * 16 + (ln & 15);
        int k = kt * 32 + ((ln >> 4) << 3) + j;
        float v = (k <= m) ? q_sqrt[m * MM + k] : 0.f;
        u16 h, lo;
        split_bf16(v, h, lo);
        Bfh[o] = h; Bfl[o] = lo;
    }
    grid.sync();

    // ---- Stage B: row sums, then alpha = 1/max ----
    for (int r = gid; r < MM; r += GT) {
        float s = 0.f;
#pragma unroll 4
        for (int j4 = 0; j4 < MM / 4; ++j4) {
            float4 v = *(const float4*)&Kuu[r * MM + 4 * j4];
            s += v.x + v.y + v.z + v.w;
        }
        rsum[r] = s;
    }
    grid.sync();
    if (blk == 0) {
        float mx = 0.f;
        for (int r = tid; r < MM; r += 256) mx = fmaxf(mx, rsum[r]);
        sbuf[tid] = mx;
        __syncthreads();
        for (int o = 128; o > 0; o >>= 1) {
            if (tid < o) sbuf[tid] = fmaxf(sbuf[tid], sbuf[tid + o]);
            __syncthreads();
        }
        if (tid == 0) alphag[0] = 1.0f / sbuf[0];
    }
    grid.sync();

    // ---- Stage C: X0 = alpha*I, R0 = I - alpha*Kuu (frag form) ----
    float a = alphag[0];
    for (int o = gid; o < FRAG_N; o += GT) {
        int j = o & 7, ln = (o >> 3) & 63, kt = (o >> 9) % 12, mt = o / 6144;
        int m = mt * 16 + (ln & 15);
        int k = kt * 32 + ((ln >> 4) << 3) + j;
        float dg = (m == k) ? 1.f : 0.f;
        float r0 = dg - a * Kuu[m * MM + k];
        float x0 = (m == k) ? a : 0.f;
        u16 h, lo;
        split_bf16(r0, h, lo); Rh_a[o] = h; Rl_a[o] = lo;
        split_bf16(x0, h, lo); Xh_a[o] = h; Xl_a[o] = lo;
    }
    grid.sync();

    // ---- Stage D: Newton-Schulz, 7 rounds, X' = X + X@R ; R' = R@R ----
    u16 *cxh = Xh_a, *cxl = Xl_a, *nxh = Xh_b, *nxl = Xl_b;
    u16 *crh = Rh_a, *crl = Rl_a, *nrh = Rh_b, *nrl = Rl_b;
    int w = tid >> 6, l = tid & 63;
    for (int it = 0; it < NS_ITERS; ++it) {
        bool isX = (blk < 36);
        int tile = isX ? blk : blk - 36;
        int bi = tile / 6, bj = tile % 6;
        floatx4 acc[2][2];
        frag_gemm64(isX ? cxh : crh, isX ? cxl : crl, crh, crl, bi, bj, w, l, acc);
        int mt0 = bi * 4 + 2 * (w & 1), nt0 = bj * 4 + 2 * (w >> 1);
        u16* Oh = isX ? nxh : nrh;
        u16* Ol = isX ? nxl : nrl;
#pragma unroll
        for (int i = 0; i < 2; ++i)
#pragma unroll
            for (int jn = 0; jn < 2; ++jn)
#pragma unroll
                for (int j = 0; j < 4; ++j) {
                    int m = (mt0 + i) * 16 + ((l >> 4) << 2) + j;
                    int p = (nt0 + jn) * 16 + (l & 15);
                    float v = acc[i][jn][j];
                    if (isX) {
                        int id = frag_idx(m, p);
                        v += bf2f(cxh[id]) + bf2f(cxl[id]);
                    }
                    dwrite_frag(Oh, Ol, m, p, v);
                }
        grid.sync();
        u16* t;
        t = cxh; cxh = nxh; nxh = t;
        t = cxl; cxl = nxl; nxl = t;
        t = crh; crh = nrh; nrh = t;
        t = crl; crl = nrl; nrl = t;
    }
    // X final in cxh/cxl; nxh/nxl (a-slots) free -> SK target.
    u16* SKh = nxh;
    u16* SKl = nxl;
    u16* Yh = (u16*)Kuu;            // Kuu region free after SK computed
    u16* Yl = Yh + FRAG_N;

    // ---- Stage E: blocks 0-35: SK = Q@Q^T - Kuu ; blocks 36-41: cvec = X@q_mu ----
    if (blk < 36) {
        int bi = blk / 6, bj = blk % 6;
        floatx4 acc[2][2];
        frag_gemm64(Bfh, Bfl, Bfh, Bfl, bi, bj, w, l, acc);   // Q @ Q^T
        int mt0 = bi * 4 + 2 * (w & 1), nt0 = bj * 4 + 2 * (w >> 1);
#pragma unroll
        for (int i = 0; i < 2; ++i)
#pragma unroll
            for (int jn = 0; jn < 2; ++jn)
#pragma unroll
                for (int j = 0; j < 4; ++j) {
                    int m = (mt0 + i) * 16 + ((l >> 4) << 2) + j;
                    int p = (nt0 + jn) * 16 + (l & 15);
                    dwrite_frag(SKh, SKl, m, p, acc[i][jn][j] - Kuu[m * MM + p]);
                }
    } else if (blk < 42) {
        if (tid < MM) sbuf[tid] = q_mu[tid];
        if (tid + 256 < MM) sbuf[tid + 256] = q_mu[tid + 256];
        __syncthreads();
        int mt = (blk - 36) * 4 + w;
        float s = 0.f;
        for (int kt = 0; kt < 12; ++kt) {
            int b = ((mt * 12 + kt) * 64 + l) * 8;
            short8 h8 = *(const short8*)&cxh[b];
            short8 l8 = *(const short8*)&cxl[b];
            int kb = kt * 32 + ((l >> 4) << 3);
#pragma unroll
            for (int j = 0; j < 8; ++j)
                s += (bf2f((u16)h8[j]) + bf2f((u16)l8[j])) * sbuf[kb + j];
        }
        s += __shfl_xor(s, 16);
        s += __shfl_xor(s, 32);
        if (l < 16) cvec[mt * 16 + l] = s;
    }
    grid.sync();

    // ---- Stage F: Y = X @ SK ----
    if (blk < 36) {
        int bi = blk / 6, bj = blk % 6;
        floatx4 acc[2][2];
        frag_gemm64(cxh, cxl, SKh, SKl, bi, bj, w, l, acc);
        int mt0 = bi * 4 + 2 * (w & 1), nt0 = bj * 4 + 2 * (w >> 1);
#pragma unroll
        for (int i = 0; i < 2; ++i)
#pragma unroll
            for (int jn = 0; jn < 2; ++jn)
#pragma unroll
                for (int j = 0; j < 4; ++j) {
                    int m = (mt0 + i) * 16 + ((l >> 4) << 2) + j;
                    int p = (nt0 + jn) * 16 + (l & 15);
                    dwrite_frag(Yh, Yl, m, p, acc[i][jn][j]);
                }
    }
    grid.sync();

    // ---- Stage G: Bq = Y @ X (overwrites Q in Bf region) ----
    if (blk < 36) {
        int bi = blk / 6, bj = blk % 6;
        floatx4 acc[2][2];
        frag_gemm64(Yh, Yl, cxh, cxl, bi, bj, w, l, acc);
        int mt0 = bi * 4 + 2 * (w & 1), nt0 = bj * 4 + 2 * (w >> 1);
#pragma unroll
        for (int i = 0; i < 2; ++i)
#pragma unroll
            for (int jn = 0; jn < 2; ++jn)
#pragma unroll
                for (int j = 0; j < 4; ++j) {
                    int m = (mt0 + i) * 16 + ((l >> 4) << 2) + j;
                    int p = (nt0 + jn) * 16 + (l & 15);
                    dwrite_frag(Bfh, Bfl, m, p, acc[i][jn][j]);
                }
    }
}

// ---------------------------------------------------------------------------
// Main fused kernel, 64 points/block, 512 threads.
#define KPAD 26112
__device__ inline int lds_k_off(int g, int sidx) { return g * 8 + ((g >> 4) << 3) + sidx; }
__device__ inline int k_granule(int k, int p) {
    return ((k >> 5) * 4 + (p >> 4)) * 64 + (((k >> 3) & 3) << 4) + (p & 15);
}

__global__ void __launch_bounds__(512) main_kernel(
    const float* __restrict__ Xin,
    const u16* __restrict__ Zfh, const u16* __restrict__ Zfl,
    const float* __restrict__ z2g,
    const u16* __restrict__ Bfh, const u16* __restrict__ Bfl,
    const float* __restrict__ cvec,
    const float* __restrict__ var_p, const float* __restrict__ ls_p,
    float* __restrict__ out) {
    __shared__ float patch[64 * 36];
    __shared__ float zsq[MM];
    __shared__ float cv[MM];
    __shared__ float xsq[64];
    __shared__ u16 kh[KPAD];
    __shared__ u16 kl[KPAD];
    __shared__ float red[512];

    int tid = threadIdx.x;
    int np0 = blockIdx.x * 64;
    float var = var_p[0];
    float ls = ls_p[0];
    float c0 = -0.5f / (ls * ls);

    if (tid < MM) { zsq[tid] = z2g[tid]; cv[tid] = cvec[tid]; }
    for (int e = tid; e < 64 * 36; e += 512) {
        int pt = e / 36, c = e % 36;
        float v = 0.f;
        if (c < 25) {
            int np = np0 + pt;
            int n = np / PP, p = np % PP;
            int oi = p / 36, oj = p % 36;
            v = Xin[n * (HH * WW) + (oi + c / 5) * WW + (oj + c % 5)];
        }
        patch[e] = v;
    }
    __syncthreads();
    if (tid < 64) {
        float s = 0.f;
#pragma unroll
        for (int d = 0; d < LL; ++d) { float x = patch[tid * 36 + d]; s += x * x; }
        xsq[tid] = s;
    }
    __syncthreads();

    int w = tid >> 6, l = tid & 63;

    // phase 1: cross = Z @ patch^T (split-bf16 MFMA)
    short8 pbh[4], pbl[4];
#pragma unroll
    for (int nt = 0; nt < 4; ++nt) {
        int p = nt * 16 + (l & 15);
        int pb = p * 36 + ((l >> 4) << 3);
        float4 f0 = *(const float4*)&patch[pb];
        float4 f1 = *(const float4*)&patch[pb + 4];
        float xv[8] = {f0.x, f0.y, f0.z, f0.w, f1.x, f1.y, f1.z, f1.w};
#pragma unroll
        for (int j = 0; j < 8; ++j) {
            u16 h, lo;
            split_bf16(xv[j], h, lo);
            pbh[nt][j] = (short)h;
            pbl[nt][j] = (short)lo;
        }
    }
    floatx4 acc2[3][4];
#pragma unroll
    for (int i = 0; i < 3; ++i) {
        int zt = w * 3 + i;
        short8 zah = *(const short8*)&Zfh[(zt * 64 + l) * 8];
        short8 zal = *(const short8*)&Zfl[(zt * 64 + l) * 8];
#pragma unroll
        for (int nt = 0; nt < 4; ++nt) {
            floatx4 z = {0.f, 0.f, 0.f, 0.f};
            z = __builtin_amdgcn_mfma_f32_16x16x32_bf16(zah, pbh[nt], z, 0, 0, 0);
            z = __builtin_amdgcn_mfma_f32_16x16x32_bf16(zah, pbl[nt], z, 0, 0, 0);
            z = __builtin_amdgcn_mfma_f32_16x16x32_bf16(zal, pbh[nt], z, 0, 0, 0);
            acc2[i][nt] = z;
        }
    }

    // finalize K values: keep fp32 in registers (Kreg), fold mean partials,
    // store bf16 hi/lo into LDS for phase 2.
    float Kreg[3][4][4];
    float mp[4] = {0.f, 0.f, 0.f, 0.f};
#pragma unroll
    for (int i = 0; i < 3; ++i) {
        int k0 = (w * 3 + i) * 16 + ((l >> 4) << 2);
#pragma unroll
        for (int nt = 0; nt < 4; ++nt) {
            int p = nt * 16 + (l & 15);
            u16 hi[4], lo[4];
#pragma unroll
            for (int j = 0; j < 4; ++j) {
                float s = zsq[k0 + j] + xsq[p] - 2.f * acc2[i][nt][j];
                s = fmaxf(s, 0.f);
                float v = var * __expf(s * c0);
                Kreg[i][nt][j] = v;
                mp[nt] += cv[k0 + j] * v;
                split_bf16(v, hi[j], lo[j]);
            }
            int g = k_granule(k0, p);
            int off = lds_k_off(g, k0 & 7);
            *(u32*)&kh[off]     = (u32)hi[0] | ((u32)hi[1] << 16);
            *(u32*)&kh[off + 2] = (u32)hi[2] | ((u32)hi[3] << 16);
            *(u32*)&kl[off]     = (u32)lo[0] | ((u32)lo[1] << 16);
            *(u32*)&kl[off + 2] = (u32)lo[2] | ((u32)lo[3] << 16);
        }
    }
    // wave-reduce mean partials into red
#pragma unroll
    for (int nt = 0; nt < 4; ++nt) {
        mp[nt] += __shfl_xor(mp[nt], 16);
        mp[nt] += __shfl_xor(mp[nt], 32);
    }
    if (l < 16) {
#pragma unroll
        for (int nt = 0; nt < 4; ++nt) red[w * 64 + nt * 16 + l] = mp[nt];
    }
    __syncthreads();   // publishes kh/kl AND mean partials
    if (tid < 64) {
        float s = 0.f;
#pragma unroll
        for (int ww = 0; ww < 8; ++ww) s += red[ww * 64 + tid];
        out[np0 + tid] = s;   // mean
    }

    // phase 2: acc[m][p] = sum_k Bq[m][k] K[k][p]
    floatx4 acc[3][4];
#pragma unroll
    for (int i = 0; i < 3; ++i)
#pragma unroll
        for (int nt = 0; nt < 4; ++nt) { floatx4 z = {0.f, 0.f, 0.f, 0.f}; acc[i][nt] = z; }
    for (int kt = 0; kt < 12; ++kt) {
        short8 bh[4], bl[4];
#pragma unroll
        for (int nt = 0; nt < 4; ++nt) {
            int g = (kt * 4 + nt) * 64 + l;
            int off = lds_k_off(g, 0);
            bh[nt] = *(const short8*)&kh[off];
            bl[nt] = *(const short8*)&kl[off];
        }
#pragma unroll
        for (int i = 0; i < 3; ++i) {
            int mt = w * 3 + i;
            int ab = ((mt * 12 + kt) * 64 + l) * 8;
            short8 ah = *(const short8*)&Bfh[ab];
            short8 al = *(const short8*)&Bfl[ab];
#pragma unroll
            for (int nt = 0; nt < 4; ++nt) {
                acc[i][nt] = __builtin_amdgcn_mfma_f32_16x16x32_bf16(ah, bh[nt], acc[i][nt], 0, 0, 0);
                acc[i][nt] = __builtin_amdgcn_mfma_f32_16x16x32_bf16(ah, bl[nt], acc[i][nt], 0, 0, 0);
                acc[i][nt] = __builtin_amdgcn_mfma_f32_16x16x32_bf16(al, bh[nt], acc[i][nt], 0, 0, 0);
            }
        }
    }
    __syncthreads();   // mean readers done before red is overwritten

    // diag epilogue: pure-register dot of Kreg with acc (identical D-frag maps)
    float dp[4] = {0.f, 0.f, 0.f, 0.f};
#pragma unroll
    for (int i = 0; i < 3; ++i)
#pragma unroll
        for (int nt = 0; nt < 4; ++nt)
#pragma unroll
            for (int j = 0; j < 4; ++j)
                dp[nt] += Kreg[i][nt][j] * acc[i][nt][j];
#pragma unroll
    for (int nt = 0; nt < 4; ++nt) {
        dp[nt] += __shfl_xor(dp[nt], 16);
        dp[nt] += __shfl_xor(dp[nt], 32);
    }
    if (l < 16) {
#pragma unroll
        for (int nt = 0; nt < 4; ++nt) red[w * 64 + nt * 16 + l] = dp[nt];
    }
    __syncthreads();
    if (tid < 64) {
        float s = 0.f;
#pragma unroll
        for (int ww = 0; ww < 8; ++ww) s += red[ww * 64 + tid];
        out[NPTS + np0 + tid] = var + s;
    }
}

// ---------------------------------------------------------------------------
extern "C" void kernel_launch(void* const* d_in, const int* in_sizes, int n_in,
                              void* d_out, int out_size, void* d_ws, size_t ws_size,
                              hipStream_t stream) {
    const float* Xin    = (const float*)d_in[0];
    const float* Z      = (const float*)d_in[1];
    const float* q_mu   = (const float*)d_in[2];
    const float* q_sqrt = (const float*)d_in[3];
    const float* var_p  = (const float*)d_in[4];
    const float* ls_p   = (const float*)d_in[5];
    float* out = (float*)d_out;

    const size_t HB = (size_t)FRAG_N * 2;  // 294912 B per frag half-array
    char* base = (char*)d_ws;
    float* Kuu = (float*)base;                 // 2*HB (later Y frags)
    u16* Xh_a = (u16*)(base + 2 * HB);
    u16* Xl_a = (u16*)(base + 3 * HB);
    u16* Xh_b = (u16*)(base + 4 * HB);
    u16* Xl_b = (u16*)(base + 5 * HB);
    u16* Rh_a = (u16*)(base + 6 * HB);
    u16* Rl_a = (u16*)(base + 7 * HB);
    u16* Rh_b = (u16*)(base + 8 * HB);
    u16* Rl_b = (u16*)(base + 9 * HB);
    u16* Bfh  = (u16*)(base + 10 * HB);        // Q frags, then Bq frags
    u16* Bfl  = (u16*)(base + 11 * HB);
    char* pF = base + 12 * HB;
    u16* Zfh = (u16*)pF;
    u16* Zfl = (u16*)(pF + ZFRAG_N * 2);
    float* z2g   = (float*)(pF + ZFRAG_N * 4);
    float* cvec  = z2g + MM;
    float* rsum  = cvec + MM;
    float* alphag = rsum + MM;

    void* args[] = {
        (void*)&Z, (void*)&q_mu, (void*)&q_sqrt, (void*)&var_p, (void*)&ls_p,
        (void*)&Kuu,
        (void*)&Xh_a, (void*)&Xl_a, (void*)&Xh_b, (void*)&Xl_b,
        (void*)&Rh_a, (void*)&Rl_a, (void*)&Rh_b, (void*)&Rl_b,
        (void*)&Bfh, (void*)&Bfl, (void*)&Zfh, (void*)&Zfl,
        (void*)&z2g, (void*)&cvec, (void*)&rsum, (void*)&alphag};
    hipLaunchCooperativeKernel((const void*)setup_kernel, dim3(GRID_SETUP), dim3(256),
                               args, 0, stream);

    main_kernel<<<NPTS / 64, 512, 0, stream>>>(Xin, Zfh, Zfl, z2g, Bfh, Bfl, cvec,
                                               var_p, ls_p, out);
}

// Round 5
// 218.618 us; speedup vs baseline: 1.7964x; 1.7964x over previous
//
#include <hip/hip_runtime.h>
#include <hip/hip_bf16.h>

// Problem constants
#define HH 40
#define WW 40
#define KK 5
#define PP 1296            // 36*36
#define LL 25
#define MM 384
#define NN 64
#define NPTS (NN * PP)     // 82944
#define JITTER 1e-6f

typedef unsigned short u16;
typedef unsigned int   u32;
using short8  = __attribute__((ext_vector_type(8))) short;
using floatx4 = __attribute__((ext_vector_type(4))) float;

#define FRAG_N (MM * MM)        // u16 per frag half-array (147456)
#define ZFRAG_N (24 * 64 * 8)   // 12288

// ---------------------------------------------------------------------------
// bf16 split helpers (RNE)
__device__ inline u16 f2bf(float v) {
    u32 b = __float_as_uint(v);
    return (u16)((b + 0x7FFFu + ((b >> 16) & 1u)) >> 16);
}
__device__ inline float bf2f(u16 h) { return __uint_as_float(((u32)h) << 16); }
__device__ inline void split_bf16(float v, u16& hi, u16& lo) {
    hi = f2bf(v);
    lo = f2bf(v - bf2f(hi));
}

// A-fragment linear index (u16 units) for element (m,k), HW-verified rounds 2-4.
__device__ inline int frag_idx(int m, int k) {
    return (((m >> 4) * 12 + (k >> 5)) * 64 + ((m & 15) + (((k >> 3) & 3) << 4))) * 8 + (k & 7);
}

// ---------------------------------------------------------------------------
// Split-bf16 MFMA 64x64-tile GEMM on A-frag operands (B symmetric).
__device__ inline void frag_gemm64(const u16* __restrict__ Ah, const u16* __restrict__ Al,
                                   const u16* __restrict__ Bh, const u16* __restrict__ Bl,
                                   int bi, int bj, int w, int l, floatx4 acc[2][2]) {
    int mt0 = bi * 4 + 2 * (w & 1);
    int nt0 = bj * 4 + 2 * (w >> 1);
#pragma unroll
    for (int i = 0; i < 2; ++i)
#pragma unroll
        for (int jn = 0; jn < 2; ++jn) { floatx4 z = {0.f, 0.f, 0.f, 0.f}; acc[i][jn] = z; }
    for (int kt = 0; kt < 12; ++kt) {
        int ab0 = (((mt0 + 0) * 12 + kt) * 64 + l) * 8;
        int ab1 = (((mt0 + 1) * 12 + kt) * 64 + l) * 8;
        int bb0 = (((nt0 + 0) * 12 + kt) * 64 + l) * 8;
        int bb1 = (((nt0 + 1) * 12 + kt) * 64 + l) * 8;
        short8 a0h = *(const short8*)&Ah[ab0];
        short8 a0l = *(const short8*)&Al[ab0];
        short8 a1h = *(const short8*)&Ah[ab1];
        short8 a1l = *(const short8*)&Al[ab1];
        short8 b0h = *(const short8*)&Bh[bb0];
        short8 b0l = *(const short8*)&Bl[bb0];
        short8 b1h = *(const short8*)&Bh[bb1];
        short8 b1l = *(const short8*)&Bl[bb1];
        acc[0][0] = __builtin_amdgcn_mfma_f32_16x16x32_bf16(a0h, b0h, acc[0][0], 0, 0, 0);
        acc[0][0] = __builtin_amdgcn_mfma_f32_16x16x32_bf16(a0h, b0l, acc[0][0], 0, 0, 0);
        acc[0][0] = __builtin_amdgcn_mfma_f32_16x16x32_bf16(a0l, b0h, acc[0][0], 0, 0, 0);
        acc[0][1] = __builtin_amdgcn_mfma_f32_16x16x32_bf16(a0h, b1h, acc[0][1], 0, 0, 0);
        acc[0][1] = __builtin_amdgcn_mfma_f32_16x16x32_bf16(a0h, b1l, acc[0][1], 0, 0, 0);
        acc[0][1] = __builtin_amdgcn_mfma_f32_16x16x32_bf16(a0l, b1h, acc[0][1], 0, 0, 0);
        acc[1][0] = __builtin_amdgcn_mfma_f32_16x16x32_bf16(a1h, b0h, acc[1][0], 0, 0, 0);
        acc[1][0] = __builtin_amdgcn_mfma_f32_16x16x32_bf16(a1h, b0l, acc[1][0], 0, 0, 0);
        acc[1][0] = __builtin_amdgcn_mfma_f32_16x16x32_bf16(a1l, b0h, acc[1][0], 0, 0, 0);
        acc[1][1] = __builtin_amdgcn_mfma_f32_16x16x32_bf16(a1h, b1h, acc[1][1], 0, 0, 0);
        acc[1][1] = __builtin_amdgcn_mfma_f32_16x16x32_bf16(a1h, b1l, acc[1][1], 0, 0, 0);
        acc[1][1] = __builtin_amdgcn_mfma_f32_16x16x32_bf16(a1l, b1h, acc[1][1], 0, 0, 0);
    }
}

__device__ inline void dwrite_frag(u16* __restrict__ Oh, u16* __restrict__ Ol,
                                   int m, int p, float v) {
    int idx = frag_idx(m, p);
    u16 hi, lo;
    split_bf16(v, hi, lo);
    Oh[idx] = hi; Ol[idx] = lo;
}

// R0 = I - alpha*Kuu fragment (row works for A and B side: R0 symmetric)
__device__ inline void load_r0(const float* __restrict__ Kuu, float alpha,
                               int row, int kt, int l, short8& h8, short8& l8) {
    int kb = kt * 32 + ((l >> 4) << 3);
    const float* p = &Kuu[row * MM + kb];
    float4 f0 = *(const float4*)p;
    float4 f1 = *(const float4*)(p + 4);
    float vv[8] = {f0.x, f0.y, f0.z, f0.w, f1.x, f1.y, f1.z, f1.w};
#pragma unroll
    for (int j = 0; j < 8; ++j) {
        float r = ((row == kb + j) ? 1.f : 0.f) - alpha * vv[j];
        u16 h, lo;
        split_bf16(r, h, lo);
        h8[j] = (short)h; l8[j] = (short)lo;
    }
}

// ---------------------------------------------------------------------------
// Launch 1: Kuu + rowsums + z2 + Z frags + Q frags, one block per Kuu row.
__global__ void __launch_bounds__(384) prep_kernel(
    const float* __restrict__ Z, const float* __restrict__ q_sqrt,
    const float* __restrict__ var_p, const float* __restrict__ ls_p,
    float* __restrict__ Kuu, float* __restrict__ rsum, float* __restrict__ z2g,
    u16* __restrict__ Qh, u16* __restrict__ Ql,
    u16* __restrict__ Zfh, u16* __restrict__ Zfl) {
    __shared__ float Zs[LL];
    __shared__ float red[384];
    int r = blockIdx.x, tid = threadIdx.x;
    if (tid < LL) Zs[tid] = Z[r * LL + tid];
    __syncthreads();
    float var = var_p[0];
    float ls = ls_p[0];
    float c0 = -0.5f / (ls * ls);
    float s = 0.f;
#pragma unroll
    for (int d = 0; d < LL; ++d) {
        float dd = Zs[d] - Z[tid * LL + d];
        s += dd * dd;
    }
    float v = var * expf(c0 * s);
    if (tid == r) v += JITTER;
    Kuu[r * MM + tid] = v;
    red[tid] = v;
    __syncthreads();
    if (tid < 128) red[tid] += red[tid + 256];
    __syncthreads();
    for (int o = 128; o > 0; o >>= 1) {
        if (tid < o) red[tid] += red[tid + o];
        __syncthreads();
    }
    if (tid == 0) {
        rsum[r] = red[0];
        float t = 0.f;
#pragma unroll
        for (int d = 0; d < LL; ++d) t += Zs[d] * Zs[d];
        z2g[r] = t;
    }
    // Q frags: one element per thread (384*384 == FRAG_N)
    {
        int o = r * MM + tid;
        int j = o & 7, ln = (o >> 3) & 63, kt = (o >> 9) % 12, mt = o / 6144;
        int m = mt * 16 + (ln & 15);
        int k = kt * 32 + ((ln >> 4) << 3) + j;
        float qv = (k <= m) ? q_sqrt[m * MM + k] : 0.f;
        u16 h, lo;
        split_bf16(qv, h, lo);
        Qh[o] = h; Ql[o] = lo;
        // Z frags
        if (o < ZFRAG_N) {
            int zt = o >> 9;
            int mz = zt * 16 + (ln & 15);
            int kd = ((ln >> 4) << 3) + j;
            float zv = (kd < LL) ? Z[mz * LL + kd] : 0.f;
            split_bf16(zv, h, lo);
            Zfh[o] = h; Zfl[o] = lo;
        }
    }
}

// ---------------------------------------------------------------------------
// Launch 2: blocks 0-35: X1 = alpha*(2I - alpha*Kuu) elementwise;
//           blocks 36-71: R1 = R0 @ R0 (R0 frags built on the fly);
//           blocks 72-107: SK = Q@Q^T - Kuu.
__global__ void __launch_bounds__(256) ns1_kernel(
    const float* __restrict__ Kuu, const float* __restrict__ rsum,
    const u16* __restrict__ Qh, const u16* __restrict__ Ql,
    u16* __restrict__ Xh, u16* __restrict__ Xl,
    u16* __restrict__ Rh, u16* __restrict__ Rl,
    u16* __restrict__ SKh, u16* __restrict__ SKl) {
    __shared__ float red[256];
    int tid = threadIdx.x, blk = blockIdx.x;
    int w = tid >> 6, l = tid & 63;
    float alpha = 0.f;
    if (blk < 72) {  // need alpha: reduce max rowsum locally
        float v = rsum[tid];
        if (tid < 128) v = fmaxf(v, rsum[tid + 256]);
        red[tid] = v;
        __syncthreads();
        for (int o = 128; o > 0; o >>= 1) {
            if (tid < o) red[tid] = fmaxf(red[tid], red[tid + o]);
            __syncthreads();
        }
        alpha = 1.0f / red[0];
    }
    if (blk < 36) {
        float a2 = alpha * alpha;
        for (int o = blk * 256 + tid; o < FRAG_N; o += 36 * 256) {
            int j = o & 7, ln = (o >> 3) & 63, kt = (o >> 9) % 12, mt = o / 6144;
            int m = mt * 16 + (ln & 15);
            int k = kt * 32 + ((ln >> 4) << 3) + j;
            float v = ((m == k) ? 2.f * alpha : 0.f) - a2 * Kuu[m * MM + k];
            u16 h, lo;
            split_bf16(v, h, lo);
            Xh[o] = h; Xl[o] = lo;
        }
    } else if (blk < 72) {
        int tile = blk - 36;
        int bi = tile / 6, bj = tile % 6;
        int mt0 = bi * 4 + 2 * (w & 1), nt0 = bj * 4 + 2 * (w >> 1);
        floatx4 acc[2][2];
#pragma unroll
        for (int i = 0; i < 2; ++i)
#pragma unroll
            for (int jn = 0; jn < 2; ++jn) { floatx4 z = {0.f,0.f,0.f,0.f}; acc[i][jn] = z; }
        for (int kt = 0; kt < 12; ++kt) {
            short8 a0h, a0l, a1h, a1l, b0h, b0l, b1h, b1l;
            load_r0(Kuu, alpha, (mt0 + 0) * 16 + (l & 15), kt, l, a0h, a0l);
            load_r0(Kuu, alpha, (mt0 + 1) * 16 + (l & 15), kt, l, a1h, a1l);
            load_r0(Kuu, alpha, (nt0 + 0) * 16 + (l & 15), kt, l, b0h, b0l);
            load_r0(Kuu, alpha, (nt0 + 1) * 16 + (l & 15), kt, l, b1h, b1l);
            acc[0][0] = __builtin_amdgcn_mfma_f32_16x16x32_bf16(a0h, b0h, acc[0][0], 0, 0, 0);
            acc[0][0] = __builtin_amdgcn_mfma_f32_16x16x32_bf16(a0h, b0l, acc[0][0], 0, 0, 0);
            acc[0][0] = __builtin_amdgcn_mfma_f32_16x16x32_bf16(a0l, b0h, acc[0][0], 0, 0, 0);
            acc[0][1] = __builtin_amdgcn_mfma_f32_16x16x32_bf16(a0h, b1h, acc[0][1], 0, 0, 0);
            acc[0][1] = __builtin_amdgcn_mfma_f32_16x16x32_bf16(a0h, b1l, acc[0][1], 0, 0, 0);
            acc[0][1] = __builtin_amdgcn_mfma_f32_16x16x32_bf16(a0l, b1h, acc[0][1], 0, 0, 0);
            acc[1][0] = __builtin_amdgcn_mfma_f32_16x16x32_bf16(a1h, b0h, acc[1][0], 0, 0, 0);
            acc[1][0] = __builtin_amdgcn_mfma_f32_16x16x32_bf16(a1h, b0l, acc[1][0], 0, 0, 0);
            acc[1][0] = __builtin_amdgcn_mfma_f32_16x16x32_bf16(a1l, b0h, acc[1][0], 0, 0, 0);
            acc[1][1] = __builtin_amdgcn_mfma_f32_16x16x32_bf16(a1h, b1h, acc[1][1], 0, 0, 0);
            acc[1][1] = __builtin_amdgcn_mfma_f32_16x16x32_bf16(a1h, b1l, acc[1][1], 0, 0, 0);
            acc[1][1] = __builtin_amdgcn_mfma_f32_16x16x32_bf16(a1l, b1h, acc[1][1], 0, 0, 0);
        }
#pragma unroll
        for (int i = 0; i < 2; ++i)
#pragma unroll
            for (int jn = 0; jn < 2; ++jn)
#pragma unroll
                for (int j = 0; j < 4; ++j) {
                    int m = (mt0 + i) * 16 + ((l >> 4) << 2) + j;
                    int p = (nt0 + jn) * 16 + (l & 15);
                    dwrite_frag(Rh, Rl, m, p, acc[i][jn][j]);
                }
    } else {
        int tile = blk - 72;
        int bi = tile / 6, bj = tile % 6;
        floatx4 acc[2][2];
        frag_gemm64(Qh, Ql, Qh, Ql, bi, bj, w, l, acc);
        int mt0 = bi * 4 + 2 * (w & 1), nt0 = bj * 4 + 2 * (w >> 1);
#pragma unroll
        for (int i = 0; i < 2; ++i)
#pragma unroll
            for (int jn = 0; jn < 2; ++jn)
#pragma unroll
                for (int j = 0; j < 4; ++j) {
                    int m = (mt0 + i) * 16 + ((l >> 4) << 2) + j;
                    int p = (nt0 + jn) * 16 + (l & 15);
                    dwrite_frag(SKh, SKl, m, p, acc[i][jn][j] - Kuu[m * MM + p]);
                }
    }
}

// ---------------------------------------------------------------------------
// NS rounds 2..7: blocks 0-35: X' = X + X@R ; 36-71: R' = R@R
__global__ void __launch_bounds__(256) ns_kernel(
    const u16* __restrict__ cxh, const u16* __restrict__ cxl,
    const u16* __restrict__ crh, const u16* __restrict__ crl,
    u16* __restrict__ nxh, u16* __restrict__ nxl,
    u16* __restrict__ nrh, u16* __restrict__ nrl) {
    int blk = blockIdx.x, tid = threadIdx.x;
    bool isX = (blk < 36);
    int tile = isX ? blk : blk - 36;
    int bi = tile / 6, bj = tile % 6;
    int w = tid >> 6, l = tid & 63;
    floatx4 acc[2][2];
    frag_gemm64(isX ? cxh : crh, isX ? cxl : crl, crh, crl, bi, bj, w, l, acc);
    int mt0 = bi * 4 + 2 * (w & 1), nt0 = bj * 4 + 2 * (w >> 1);
    u16* Oh = isX ? nxh : nrh;
    u16* Ol = isX ? nxl : nrl;
#pragma unroll
    for (int i = 0; i < 2; ++i)
#pragma unroll
        for (int jn = 0; jn < 2; ++jn)
#pragma unroll
            for (int j = 0; j < 4; ++j) {
                int m = (mt0 + i) * 16 + ((l >> 4) << 2) + j;
                int p = (nt0 + jn) * 16 + (l & 15);
                float v = acc[i][jn][j];
                if (isX) {
                    int id = frag_idx(m, p);
                    v += bf2f(cxh[id]) + bf2f(cxl[id]);
                }
                dwrite_frag(Oh, Ol, m, p, v);
            }
}

// ---------------------------------------------------------------------------
// Launch 9: blocks 0-35: Y = X @ SK ; blocks 36-41: cvec = X @ q_mu
__global__ void __launch_bounds__(256) y_kernel(
    const u16* __restrict__ Xh, const u16* __restrict__ Xl,
    const u16* __restrict__ SKh, const u16* __restrict__ SKl,
    const float* __restrict__ qmu,
    u16* __restrict__ Yh, u16* __restrict__ Yl, float* __restrict__ cvec) {
    __shared__ float q[MM];
    int tid = threadIdx.x, blk = blockIdx.x;
    int w = tid >> 6, l = tid & 63;
    if (blk < 36) {
        int bi = blk / 6, bj = blk % 6;
        floatx4 acc[2][2];
        frag_gemm64(Xh, Xl, SKh, SKl, bi, bj, w, l, acc);
        int mt0 = bi * 4 + 2 * (w & 1), nt0 = bj * 4 + 2 * (w >> 1);
#pragma unroll
        for (int i = 0; i < 2; ++i)
#pragma unroll
            for (int jn = 0; jn < 2; ++jn)
#pragma unroll
                for (int j = 0; j < 4; ++j) {
                    int m = (mt0 + i) * 16 + ((l >> 4) << 2) + j;
                    int p = (nt0 + jn) * 16 + (l & 15);
                    dwrite_frag(Yh, Yl, m, p, acc[i][jn][j]);
                }
    } else {
        if (tid < MM) q[tid] = qmu[tid];
        if (tid + 256 < MM) q[tid + 256] = qmu[tid + 256];
        __syncthreads();
        int mt = (blk - 36) * 4 + w;
        float s = 0.f;
        for (int kt = 0; kt < 12; ++kt) {
            int b = ((mt * 12 + kt) * 64 + l) * 8;
            short8 h8 = *(const short8*)&Xh[b];
            short8 l8 = *(const short8*)&Xl[b];
            int kb = kt * 32 + ((l >> 4) << 3);
#pragma unroll
            for (int j = 0; j < 8; ++j)
                s += (bf2f((u16)h8[j]) + bf2f((u16)l8[j])) * q[kb + j];
        }
        s += __shfl_xor(s, 16);
        s += __shfl_xor(s, 32);
        if (l < 16) cvec[mt * 16 + l] = s;
    }
}

// Launch 10: Bq = Y @ X
__global__ void __launch_bounds__(256) bq_kernel(
    const u16* __restrict__ Yh, const u16* __restrict__ Yl,
    const u16* __restrict__ Xh, const u16* __restrict__ Xl,
    u16* __restrict__ Bh, u16* __restrict__ Bl) {
    int blk = blockIdx.x, tid = threadIdx.x;
    int bi = blk / 6, bj = blk % 6;
    int w = tid >> 6, l = tid & 63;
    floatx4 acc[2][2];
    frag_gemm64(Yh, Yl, Xh, Xl, bi, bj, w, l, acc);
    int mt0 = bi * 4 + 2 * (w & 1), nt0 = bj * 4 + 2 * (w >> 1);
#pragma unroll
    for (int i = 0; i < 2; ++i)
#pragma unroll
        for (int jn = 0; jn < 2; ++jn)
#pragma unroll
            for (int j = 0; j < 4; ++j) {
                int m = (mt0 + i) * 16 + ((l >> 4) << 2) + j;
                int p = (nt0 + jn) * 16 + (l & 15);
                dwrite_frag(Bh, Bl, m, p, acc[i][jn][j]);
            }
}

// ---------------------------------------------------------------------------
// Main fused kernel, 64 points/block, 512 threads.
// K-tile LDS = exactly the phase-2 B-fragment layout (hi only):
//   cell(kt,nt,lane) at u16 offset ((kt*4+nt)*64 + lane)*8, holding
//   K[kt*32 + 8*(lane>>4) + j][nt*16 + (lane&15)], j=0..7.
__global__ void __launch_bounds__(512) main_kernel(
    const float* __restrict__ Xin,
    const u16* __restrict__ Zfh, const u16* __restrict__ Zfl,
    const float* __restrict__ z2g,
    const u16* __restrict__ Bfh, const u16* __restrict__ Bfl,
    const float* __restrict__ cvec,
    const float* __restrict__ var_p, const float* __restrict__ ls_p,
    float* __restrict__ out) {
    __shared__ float patch[64 * 36];
    __shared__ float zsq[MM];
    __shared__ float cv[MM];
    __shared__ float xsq[64];
    __shared__ u16 kh[12 * 4 * 64 * 8];   // 24576 u16 = 48 KB
    __shared__ float red[512];

    int tid = threadIdx.x;
    int np0 = blockIdx.x * 64;
    float var = var_p[0];
    float ls = ls_p[0];
    float c0 = -0.5f / (ls * ls);

    if (tid < MM) { zsq[tid] = z2g[tid]; cv[tid] = cvec[tid]; }
    for (int e = tid; e < 64 * 36; e += 512) {
        int pt = e / 36, c = e % 36;
        float v = 0.f;
        if (c < 25) {
            int np = np0 + pt;
            int n = np / PP, p = np % PP;
            int oi = p / 36, oj = p % 36;
            v = Xin[n * (HH * WW) + (oi + c / 5) * WW + (oj + c % 5)];
        }
        patch[e] = v;
    }
    __syncthreads();
    if (tid < 64) {
        float s = 0.f;
#pragma unroll
        for (int d = 0; d < LL; ++d) { float x = patch[tid * 36 + d]; s += x * x; }
        xsq[tid] = s;
    }
    __syncthreads();

    int w = tid >> 6, l = tid & 63;

    // phase 1: cross = Z @ patch^T (split-bf16 MFMA, 3-term)
    short8 pbh[4], pbl[4];
#pragma unroll
    for (int nt = 0; nt < 4; ++nt) {
        int p = nt * 16 + (l & 15);
        int pb = p * 36 + ((l >> 4) << 3);
        float4 f0 = *(const float4*)&patch[pb];
        float4 f1 = *(const float4*)&patch[pb + 4];
        float xv[8] = {f0.x, f0.y, f0.z, f0.w, f1.x, f1.y, f1.z, f1.w};
#pragma unroll
        for (int j = 0; j < 8; ++j) {
            u16 h, lo;
            split_bf16(xv[j], h, lo);
            pbh[nt][j] = (short)h;
            pbl[nt][j] = (short)lo;
        }
    }
    floatx4 acc2[3][4];
#pragma unroll
    for (int i = 0; i < 3; ++i) {
        int zt = w * 3 + i;
        short8 zah = *(const short8*)&Zfh[(zt * 64 + l) * 8];
        short8 zal = *(const short8*)&Zfl[(zt * 64 + l) * 8];
#pragma unroll
        for (int nt = 0; nt < 4; ++nt) {
            floatx4 z = {0.f, 0.f, 0.f, 0.f};
            z = __builtin_amdgcn_mfma_f32_16x16x32_bf16(zah, pbh[nt], z, 0, 0, 0);
            z = __builtin_amdgcn_mfma_f32_16x16x32_bf16(zah, pbl[nt], z, 0, 0, 0);
            z = __builtin_amdgcn_mfma_f32_16x16x32_bf16(zal, pbh[nt], z, 0, 0, 0);
            acc2[i][nt] = z;
        }
    }

    // finalize K: fp32 in registers, fold mean partials, bf16(hi) into LDS
    // at exactly the B-frag cell phase 2 reads.
    float Kreg[3][4][4];
    float mp[4] = {0.f, 0.f, 0.f, 0.f};
#pragma unroll
    for (int i = 0; i < 3; ++i) {
        int a2 = w * 3 + i;
        int u = l >> 4;
        int kt = a2 >> 1;
        int rr = 2 * (a2 & 1) + (u >> 1);
        int k0 = a2 * 16 + 4 * u;
#pragma unroll
        for (int nt = 0; nt < 4; ++nt) {
            int p = nt * 16 + (l & 15);
            u16 hi[4];
#pragma unroll
            for (int j = 0; j < 4; ++j) {
                float s = zsq[k0 + j] + xsq[p] - 2.f * acc2[i][nt][j];
                s = fmaxf(s, 0.f);
                float v = var * __expf(s * c0);
                Kreg[i][nt][j] = v;
                mp[nt] += cv[k0 + j] * v;
                hi[j] = f2bf(v);
            }
            int base = ((kt * 4 + nt) * 64 + rr * 16 + (l & 15)) * 8 + 4 * (u & 1);
            *(u32*)&kh[base]     = (u32)hi[0] | ((u32)hi[1] << 16);
            *(u32*)&kh[base + 2] = (u32)hi[2] | ((u32)hi[3] << 16);
        }
    }
#pragma unroll
    for (int nt = 0; nt < 4; ++nt) {
        mp[nt] += __shfl_xor(mp[nt], 16);
        mp[nt] += __shfl_xor(mp[nt], 32);
    }
    if (l < 16) {
#pragma unroll
        for (int nt = 0; nt < 4; ++nt) red[w * 64 + nt * 16 + l] = mp[nt];
    }
    __syncthreads();   // publishes kh AND mean partials
    if (tid < 64) {
        float s = 0.f;
#pragma unroll
        for (int ww = 0; ww < 8; ++ww) s += red[ww * 64 + tid];
        out[np0 + tid] = s;   // mean
    }

    // phase 2: acc[m][p] = sum_k Bq[m][k] K[k][p]; B split 2-term, K hi only
    floatx4 acc[3][4];
#pragma unroll
    for (int i = 0; i < 3; ++i)
#pragma unroll
        for (int nt = 0; nt < 4; ++nt) { floatx4 z = {0.f, 0.f, 0.f, 0.f}; acc[i][nt] = z; }
    for (int kt = 0; kt < 12; ++kt) {
        short8 bh[4];
#pragma unroll
        for (int nt = 0; nt < 4; ++nt)
            bh[nt] = *(const short8*)&kh[((kt * 4 + nt) * 64 + l) * 8];
#pragma unroll
        for (int i = 0; i < 3; ++i) {
            int mt = w * 3 + i;
            int ab = ((mt * 12 + kt) * 64 + l) * 8;
            short8 ah = *(const short8*)&Bfh[ab];
            short8 al = *(const short8*)&Bfl[ab];
#pragma unroll
            for (int nt = 0; nt < 4; ++nt) {
                acc[i][nt] = __builtin_amdgcn_mfma_f32_16x16x32_bf16(ah, bh[nt], acc[i][nt], 0, 0, 0);
                acc[i][nt] = __builtin_amdgcn_mfma_f32_16x16x32_bf16(al, bh[nt], acc[i][nt], 0, 0, 0);
            }
        }
    }
    __syncthreads();   // mean readers done before red reuse

    // diag epilogue: register dot (identical D-frag maps for Kreg and acc)
    float dp[4] = {0.f, 0.f, 0.f, 0.f};
#pragma unroll
    for (int i = 0; i < 3; ++i)
#pragma unroll
        for (int nt = 0; nt < 4; ++nt)
#pragma unroll
            for (int j = 0; j < 4; ++j)
                dp[nt] += Kreg[i][nt][j] * acc[i][nt][j];
#pragma unroll
    for (int nt = 0; nt < 4; ++nt) {
        dp[nt] += __shfl_xor(dp[nt], 16);
        dp[nt] += __shfl_xor(dp[nt], 32);
    }
    if (l < 16) {
#pragma unroll
        for (int nt = 0; nt < 4; ++nt) red[w * 64 + nt * 16 + l] = dp[nt];
    }
    __syncthreads();
    if (tid < 64) {
        float s = 0.f;
#pragma unroll
        for (int ww = 0; ww < 8; ++ww) s += red[ww * 64 + tid];
        out[NPTS + np0 + tid] = var + s;
    }
}

// ---------------------------------------------------------------------------
extern "C" void kernel_launch(void* const* d_in, const int* in_sizes, int n_in,
                              void* d_out, int out_size, void* d_ws, size_t ws_size,
                              hipStream_t stream) {
    const float* Xin    = (const float*)d_in[0];
    const float* Z      = (const float*)d_in[1];
    const float* q_mu   = (const float*)d_in[2];
    const float* q_sqrt = (const float*)d_in[3];
    const float* var_p  = (const float*)d_in[4];
    const float* ls_p   = (const float*)d_in[5];
    float* out = (float*)d_out;

    const size_t HB = (size_t)FRAG_N * 2;  // 294912 B per frag half-array
    char* base = (char*)d_ws;
    float* Kuu = (float*)base;                 // 2 HB; Bq frags overlay later
    u16* Bqh = (u16*)base;
    u16* Bql = (u16*)(base + HB);
    u16* Xh_a = (u16*)(base + 2 * HB);
    u16* Xl_a = (u16*)(base + 3 * HB);
    u16* Xh_b = (u16*)(base + 4 * HB);
    u16* Xl_b = (u16*)(base + 5 * HB);
    u16* Rh_a = (u16*)(base + 6 * HB);
    u16* Rl_a = (u16*)(base + 7 * HB);
    u16* Rh_b = (u16*)(base + 8 * HB);
    u16* Rl_b = (u16*)(base + 9 * HB);
    u16* Qh   = (u16*)(base + 10 * HB);        // Q frags; Y overlays later
    u16* Ql   = (u16*)(base + 11 * HB);
    u16* Yh = Qh;
    u16* Yl = Ql;
    u16* SKh  = (u16*)(base + 12 * HB);
    u16* SKl  = (u16*)(base + 13 * HB);
    char* pF = base + 14 * HB;
    u16* Zfh = (u16*)pF;
    u16* Zfl = (u16*)(pF + ZFRAG_N * 2);
    float* z2g  = (float*)(pF + ZFRAG_N * 4);
    float* cvec = z2g + MM;
    float* rsum = cvec + MM;

    // 1) prep: Kuu, rowsums, z2, Z frags, Q frags
    prep_kernel<<<MM, 384, 0, stream>>>(Z, q_sqrt, var_p, ls_p, Kuu, rsum, z2g,
                                        Qh, Ql, Zfh, Zfl);
    // 2) ns1: X1 (elementwise) | R1 = R0@R0 | SK = QQ^T - Kuu
    ns1_kernel<<<108, 256, 0, stream>>>(Kuu, rsum, Qh, Ql,
                                        Xh_b, Xl_b, Rh_b, Rl_b, SKh, SKl);
    // 3-8) NS rounds 2..7 (ping-pong, start at b, end at b)
    u16 *cxh = Xh_b, *cxl = Xl_b, *nxh = Xh_a, *nxl = Xl_a;
    u16 *crh = Rh_b, *crl = Rl_b, *nrh = Rh_a, *nrl = Rl_a;
    for (int it = 0; it < 6; ++it) {
        ns_kernel<<<72, 256, 0, stream>>>(cxh, cxl, crh, crl, nxh, nxl, nrh, nrl);
        u16* t;
        t = cxh; cxh = nxh; nxh = t;
        t = cxl; cxl = nxl; nxl = t;
        t = crh; crh = nrh; nrh = t;
        t = crl; crl = nrl; nrl = t;
    }
    // final X in cxh/cxl (== Xh_b/Xl_b)
    // 9) Y = X@SK | cvec = X@q_mu
    y_kernel<<<42, 256, 0, stream>>>(cxh, cxl, SKh, SKl, q_mu, Yh, Yl, cvec);
    // 10) Bq = Y@X (into Kuu region)
    bq_kernel<<<36, 256, 0, stream>>>(Yh, Yl, cxh, cxl, Bqh, Bql);
    // 11) main
    main_kernel<<<NPTS / 64, 512, 0, stream>>>(Xin, Zfh, Zfl, z2g, Bqh, Bql, cvec,
                                               var_p, ls_p, out);
}